// Round 1
// baseline (1729.322 us; speedup 1.0000x reference)
//
#include <hip/hip_runtime.h>

#define EPS 1e-12f

// Scratch layout in d_ws (floats):
//   upA: [1024][15][16]  (padded u, col 15 is zero pad)   = 245760
//   upB: [1024][15][16]                                   = 245760
//   sig: [1024]
// Padded relation: up[c][py][px] = u[c][(py+9)%11][(px+9)%11], py,px in 0..14

__global__ __launch_bounds__(128) void norm0_kernel(const float* __restrict__ u0,
                                                    float* __restrict__ up)
{
    __shared__ float u_l[121];
    __shared__ float tmp[2];
    int c = blockIdx.x;
    int t = threadIdx.x;
    float v = 0.f;
    if (t < 121) v = u0[c * 121 + t];
    float ss = v * v;
    #pragma unroll
    for (int m = 32; m >= 1; m >>= 1) ss += __shfl_xor(ss, m, 64);
    if ((t & 63) == 0) tmp[t >> 6] = ss;
    __syncthreads();
    float total = tmp[0] + tmp[1];
    float inv = 1.f / (sqrtf(total) + EPS);
    if (t < 121) u_l[t] = v * inv;
    __syncthreads();
    for (int idx = t; idx < 240; idx += 128) {
        int py = idx >> 4, px = idx & 15;
        float w = 0.f;
        if (px < 15) {
            int y = (py + 9) % 11;
            int x = (px + 9) % 11;
            w = u_l[y * 11 + x];
        }
        up[c * 240 + idx] = w;
    }
}

// One block per output channel co. 128 threads; thread t accumulates all 121
// outputs over input channels ci = t + 128k, k=0..7. Cross-thread reduce in
// LDS, then fused L2-normalize + circular-pad re-write (and sigma on last it).
__global__ __launch_bounds__(128, 2) void conv_kernel(const float* __restrict__ W,
        const float* __restrict__ upi, float* __restrict__ upo,
        float* __restrict__ sigmas, int write_sigma)
{
    __shared__ float red[64 * 128];   // 32 KB reduction scratch
    __shared__ float u_l[121];
    int co = blockIdx.x;
    int t = threadIdx.x;

    float acc[121];
    #pragma unroll
    for (int i = 0; i < 121; ++i) acc[i] = 0.f;

    for (int k = 0; k < 8; ++k) {
        int ci = t + (k << 7);
        const float* wp = W + ((size_t)co * 1024 + (size_t)ci) * 25;
        float wr[25];
        #pragma unroll
        for (int i = 0; i < 25; ++i) wr[i] = wp[i];
        const float4* rb = (const float4*)(upi + ci * 240);
        #pragma unroll
        for (int r = 0; r < 15; ++r) {
            float4 q0 = rb[r * 4 + 0];
            float4 q1 = rb[r * 4 + 1];
            float4 q2 = rb[r * 4 + 2];
            float4 q3 = rb[r * 4 + 3];
            float row[16] = {q0.x, q0.y, q0.z, q0.w, q1.x, q1.y, q1.z, q1.w,
                             q2.x, q2.y, q2.z, q2.w, q3.x, q3.y, q3.z, q3.w};
            #pragma unroll
            for (int ky = 0; ky < 5; ++ky) {
                int y = r - ky;
                if (y < 0 || y > 10) continue;   // static: r, ky are unrolled
                #pragma unroll
                for (int kx = 0; kx < 5; ++kx) {
                    float wv = wr[ky * 5 + kx];
                    #pragma unroll
                    for (int x = 0; x < 11; ++x)
                        acc[y * 11 + x] = fmaf(row[x + kx], wv, acc[y * 11 + x]);
                }
            }
        }
    }

    // ---- cross-thread reduction of 121 partials over 128 threads ----
    // XOR-rotated layout: slot(i,t) = i*128 + ((t+i)&127) -> conflict-free
    // on both the per-i store (lanes t vary) and the per-r column read.
    #pragma unroll
    for (int i = 0; i < 64; ++i)
        red[i * 128 + ((t + i) & 127)] = acc[i];
    __syncthreads();
    float val1 = 0.f;
    if (t < 64) {
        float s = 0.f;
        for (int r = 0; r < 128; ++r) s += red[t * 128 + ((r + t) & 127)];
        val1 = s;
    }
    __syncthreads();
    #pragma unroll
    for (int i = 0; i < 57; ++i)
        red[i * 128 + ((t + i) & 127)] = acc[64 + i];
    __syncthreads();
    float val2 = 0.f;
    if (t < 57) {
        float s = 0.f;
        for (int r = 0; r < 128; ++r) s += red[t * 128 + ((r + t) & 127)];
        val2 = s;
    }

    // ---- fused epilogue: norm, sigma, normalize, circular-pad write ----
    if (t < 64) {   // wave 0 only (uniform branch)
        float ss = val1 * val1 + val2 * val2;
        #pragma unroll
        for (int m = 32; m >= 1; m >>= 1) ss += __shfl_xor(ss, m, 64);
        float norm = sqrtf(ss);
        float inv = 1.f / (norm + EPS);
        u_l[t] = val1 * inv;
        if (t < 57) u_l[64 + t] = val2 * inv;
        if (t == 0 && write_sigma) sigmas[co] = norm;
    }
    __syncthreads();
    for (int idx = t; idx < 240; idx += 128) {
        int py = idx >> 4, px = idx & 15;
        float w = 0.f;
        if (px < 15) {
            int y = (py + 9) % 11;
            int x = (px + 9) % 11;
            w = u_l[y * 11 + x];
        }
        upo[co * 240 + idx] = w;
    }
}

__global__ __launch_bounds__(256) void scale_kernel(const float* __restrict__ W,
        const float* __restrict__ sigmas, float* __restrict__ out)
{
    int co = blockIdx.x;
    float s = sigmas[co];
    const float4* src = (const float4*)(W + (size_t)co * 25600);
    float4* dst = (float4*)(out + (size_t)co * 25600);
    for (int i = threadIdx.x; i < 6400; i += 256) {
        float4 v = src[i];
        v.x /= s; v.y /= s; v.z /= s; v.w /= s;
        dst[i] = v;
    }
}

extern "C" void kernel_launch(void* const* d_in, const int* in_sizes, int n_in,
                              void* d_out, int out_size, void* d_ws, size_t ws_size,
                              hipStream_t stream)
{
    const float* W  = (const float*)d_in[0];   // (1024,1024,5,5)
    const float* u0 = (const float*)d_in[1];   // (1,1024,11,11)
    float* out = (float*)d_out;                // (1024,1024,5,5)

    float* upA = (float*)d_ws;
    float* upB = upA + 1024 * 240;
    float* sig = upB + 1024 * 240;

    hipLaunchKernelGGL(norm0_kernel, dim3(1024), dim3(128), 0, stream, u0, upA);
    hipLaunchKernelGGL(conv_kernel,  dim3(1024), dim3(128), 0, stream, W, upA, upB, sig, 0);
    hipLaunchKernelGGL(conv_kernel,  dim3(1024), dim3(128), 0, stream, W, upB, upA, sig, 0);
    hipLaunchKernelGGL(conv_kernel,  dim3(1024), dim3(128), 0, stream, W, upA, upB, sig, 1);
    hipLaunchKernelGGL(scale_kernel, dim3(1024), dim3(256), 0, stream, W, sig, out);
}

// Round 2
// 671.052 us; speedup vs baseline: 2.5770x; 2.5770x over previous
//
#include <hip/hip_runtime.h>

#define EPS 1e-12f

// Scratch layout in d_ws (floats):
//   upA: [1024][15][16]  (padded u, col 15 is zero pad)   = 245760
//   upB: [1024][15][16]                                   = 245760
//   sig: [1024]
// Padded relation: up[c][py][px] = u[c][(py+9)%11][(px+9)%11], py,px in 0..14

__global__ __launch_bounds__(128) void norm0_kernel(const float* __restrict__ u0,
                                                    float* __restrict__ up)
{
    __shared__ float u_l[121];
    __shared__ float tmp[2];
    int c = blockIdx.x;
    int t = threadIdx.x;
    float v = 0.f;
    if (t < 121) v = u0[c * 121 + t];
    float ss = v * v;
    #pragma unroll
    for (int m = 32; m >= 1; m >>= 1) ss += __shfl_xor(ss, m, 64);
    if ((t & 63) == 0) tmp[t >> 6] = ss;
    __syncthreads();
    float total = tmp[0] + tmp[1];
    float inv = 1.f / (sqrtf(total) + EPS);
    if (t < 121) u_l[t] = v * inv;
    __syncthreads();
    for (int idx = t; idx < 240; idx += 128) {
        int py = idx >> 4, px = idx & 15;
        float w = 0.f;
        if (px < 15) {
            int y = (py + 9) % 11;
            int x = (px + 9) % 11;
            w = u_l[y * 11 + x];
        }
        up[c * 240 + idx] = w;
    }
}

// One block per output channel co. 128 threads; thread t accumulates all 121
// outputs over input channels ci = t + 128k, k=0..7. Cross-thread reduce in
// LDS, then fused L2-normalize + circular-pad re-write (and sigma on last it).
//
// __launch_bounds__(128, 1): min 1 wave/EU -> VGPR cap 512. Live state is
// acc[121]+wr[25]+row regs+addr ~ 200 VGPR. R1's (128,2) made the compiler
// cap at 128 VGPR and spill acc[] -> 2 GB scratch traffic per dispatch
// (WRITE_SIZE 1.2 GB on a 1 MB-output kernel). ~200 VGPR -> 2 waves/SIMD,
// 4 blocks/CU (LDS 4x33 KB = 132 <= 160 KB).
__global__ __launch_bounds__(128, 1) void conv_kernel(const float* __restrict__ W,
        const float* __restrict__ upi, float* __restrict__ upo,
        float* __restrict__ sigmas, int write_sigma)
{
    __shared__ float red[64 * 128];   // 32 KB reduction scratch
    __shared__ float u_l[121];
    int co = blockIdx.x;
    int t = threadIdx.x;

    float acc[121];
    #pragma unroll
    for (int i = 0; i < 121; ++i) acc[i] = 0.f;

    for (int k = 0; k < 8; ++k) {
        int ci = t + (k << 7);
        const float* wp = W + ((size_t)co * 1024 + (size_t)ci) * 25;
        float wr[25];
        #pragma unroll
        for (int i = 0; i < 25; ++i) wr[i] = wp[i];
        const float4* rb = (const float4*)(upi + ci * 240);
        #pragma unroll
        for (int r = 0; r < 15; ++r) {
            float4 q0 = rb[r * 4 + 0];
            float4 q1 = rb[r * 4 + 1];
            float4 q2 = rb[r * 4 + 2];
            float4 q3 = rb[r * 4 + 3];
            float row[16] = {q0.x, q0.y, q0.z, q0.w, q1.x, q1.y, q1.z, q1.w,
                             q2.x, q2.y, q2.z, q2.w, q3.x, q3.y, q3.z, q3.w};
            #pragma unroll
            for (int ky = 0; ky < 5; ++ky) {
                int y = r - ky;
                if (y < 0 || y > 10) continue;   // static: r, ky are unrolled
                #pragma unroll
                for (int kx = 0; kx < 5; ++kx) {
                    float wv = wr[ky * 5 + kx];
                    #pragma unroll
                    for (int x = 0; x < 11; ++x)
                        acc[y * 11 + x] = fmaf(row[x + kx], wv, acc[y * 11 + x]);
                }
            }
        }
    }

    // ---- cross-thread reduction of 121 partials over 128 threads ----
    // XOR-rotated layout: slot(i,t) = i*128 + ((t+i)&127) -> conflict-free
    // on both the per-i store (lanes t vary) and the per-r column read.
    #pragma unroll
    for (int i = 0; i < 64; ++i)
        red[i * 128 + ((t + i) & 127)] = acc[i];
    __syncthreads();
    float val1 = 0.f;
    if (t < 64) {
        float s = 0.f;
        for (int r = 0; r < 128; ++r) s += red[t * 128 + ((r + t) & 127)];
        val1 = s;
    }
    __syncthreads();
    #pragma unroll
    for (int i = 0; i < 57; ++i)
        red[i * 128 + ((t + i) & 127)] = acc[64 + i];
    __syncthreads();
    float val2 = 0.f;
    if (t < 57) {
        float s = 0.f;
        for (int r = 0; r < 128; ++r) s += red[t * 128 + ((r + t) & 127)];
        val2 = s;
    }

    // ---- fused epilogue: norm, sigma, normalize, circular-pad write ----
    if (t < 64) {   // wave 0 only (uniform branch)
        float ss = val1 * val1 + val2 * val2;
        #pragma unroll
        for (int m = 32; m >= 1; m >>= 1) ss += __shfl_xor(ss, m, 64);
        float norm = sqrtf(ss);
        float inv = 1.f / (norm + EPS);
        u_l[t] = val1 * inv;
        if (t < 57) u_l[64 + t] = val2 * inv;
        if (t == 0 && write_sigma) sigmas[co] = norm;
    }
    __syncthreads();
    for (int idx = t; idx < 240; idx += 128) {
        int py = idx >> 4, px = idx & 15;
        float w = 0.f;
        if (px < 15) {
            int y = (py + 9) % 11;
            int x = (px + 9) % 11;
            w = u_l[y * 11 + x];
        }
        upo[co * 240 + idx] = w;
    }
}

__global__ __launch_bounds__(256) void scale_kernel(const float* __restrict__ W,
        const float* __restrict__ sigmas, float* __restrict__ out)
{
    int co = blockIdx.x;
    float inv = 1.f / sigmas[co];     // one precise divide; then multiply
    const float4* src = (const float4*)(W + (size_t)co * 25600);
    float4* dst = (float4*)(out + (size_t)co * 25600);
    for (int i = threadIdx.x; i < 6400; i += 256) {
        float4 v = src[i];
        v.x *= inv; v.y *= inv; v.z *= inv; v.w *= inv;
        dst[i] = v;
    }
}

extern "C" void kernel_launch(void* const* d_in, const int* in_sizes, int n_in,
                              void* d_out, int out_size, void* d_ws, size_t ws_size,
                              hipStream_t stream)
{
    const float* W  = (const float*)d_in[0];   // (1024,1024,5,5)
    const float* u0 = (const float*)d_in[1];   // (1,1024,11,11)
    float* out = (float*)d_out;                // (1024,1024,5,5)

    float* upA = (float*)d_ws;
    float* upB = upA + 1024 * 240;
    float* sig = upB + 1024 * 240;

    hipLaunchKernelGGL(norm0_kernel, dim3(1024), dim3(128), 0, stream, u0, upA);
    hipLaunchKernelGGL(conv_kernel,  dim3(1024), dim3(128), 0, stream, W, upA, upB, sig, 0);
    hipLaunchKernelGGL(conv_kernel,  dim3(1024), dim3(128), 0, stream, W, upB, upA, sig, 0);
    hipLaunchKernelGGL(conv_kernel,  dim3(1024), dim3(128), 0, stream, W, upA, upB, sig, 1);
    hipLaunchKernelGGL(scale_kernel, dim3(1024), dim3(256), 0, stream, W, sig, out);
}